// Round 1
// 1140.495 us; speedup vs baseline: 1.0847x; 1.0847x over previous
//
#include <hip/hip_runtime.h>
#include <hip/hip_bf16.h>

typedef __hip_bfloat16 bf16;
typedef __attribute__((ext_vector_type(8))) short s16x8;
typedef __attribute__((ext_vector_type(4))) short s16x4;
typedef __attribute__((ext_vector_type(4))) float f32x4;

#define TT 64
#define NN_ 1024
#define EE 512

__device__ __forceinline__ float toF(float v) { return v; }
__device__ __forceinline__ float toF(bf16 v) { return __bfloat162float(v); }
__device__ __forceinline__ bf16 f2b(float v) { return __float2bfloat16(v); }

enum { EPI_F32 = 0, EPI_SIG_F32 = 1 };
enum { E_LN1 = 0, E_BF16 = 1, E_LN2 = 2, E_SILU = 3, E_OUT = 4, E_TRI = 5, E_BF16T = 6 };

// ---------------- small fp32 tiled GEMM (S0-S2 only; 1024-row problems) -------------
template <bool TRANSB, int EPI>
__global__ __launch_bounds__(256) void gemm_k(
    const float* __restrict__ A, const float* __restrict__ B,
    float* __restrict__ outF, const float* __restrict__ bias,
    const float* __restrict__ sbeta, float alpha,
    int M, int Nn, int K, int lda, int ldb)
{
    __shared__ float As[16][68];
    __shared__ float Bs[16][68];
    const int tid = threadIdx.x;
    const int tx = tid & 15, ty = tid >> 4;
    const int m0 = blockIdx.x * 64, n0 = blockIdx.y * 64;
    float acc[4][4] = {};

    for (int k0 = 0; k0 < K; k0 += 16) {
        {
            int row = tid >> 2, kk0 = (tid & 3) * 4, grow = m0 + row;
#pragma unroll
            for (int j = 0; j < 4; j++) {
                int kk = kk0 + j, gk = k0 + kk;
                As[kk][row] = (grow < M) ? A[(size_t)grow * lda + gk] : 0.f;
            }
        }
        if (!TRANSB) {
            int kk = tid >> 4, c0 = (tid & 15) * 4;
#pragma unroll
            for (int j = 0; j < 4; j++) {
                int col = c0 + j, gn = n0 + col;
                Bs[kk][col] = (gn < Nn) ? B[(size_t)(k0 + kk) * ldb + gn] : 0.f;
            }
        } else {
            int col = tid >> 2, kk0 = (tid & 3) * 4, gn = n0 + col;
#pragma unroll
            for (int j = 0; j < 4; j++) {
                int kk = kk0 + j;
                Bs[kk][col] = (gn < Nn) ? B[(size_t)gn * ldb + (k0 + kk)] : 0.f;
            }
        }
        __syncthreads();
#pragma unroll
        for (int kk = 0; kk < 16; kk++) {
            float a[4], b[4];
#pragma unroll
            for (int i = 0; i < 4; i++) a[i] = As[kk][ty * 4 + i];
#pragma unroll
            for (int j = 0; j < 4; j++) b[j] = Bs[kk][tx * 4 + j];
#pragma unroll
            for (int i = 0; i < 4; i++)
#pragma unroll
                for (int j = 0; j < 4; j++)
                    acc[i][j] = fmaf(a[i], b[j], acc[i][j]);
        }
        __syncthreads();
    }

    float gb = (EPI == EPI_SIG_F32 && sbeta) ? sbeta[0] : 0.f;
#pragma unroll
    for (int i = 0; i < 4; i++) {
        int row = m0 + ty * 4 + i;
        if (row >= M) continue;
#pragma unroll
        for (int j = 0; j < 4; j++) {
            int col = n0 + tx * 4 + j;
            if (col >= Nn) continue;
            float v = acc[i][j];
            if (EPI == EPI_F32) {
                if (bias) v += bias[col];
                outF[(size_t)row * Nn + col] = v;
            } else {
                v = v * alpha + gb;
                outF[(size_t)row * Nn + col] = 1.f / (1.f + __expf(-v));
            }
        }
    }
}

// ---------------- MFMA bf16 GEMM -----------------------------------------------------
// C[M,Nn] = A[M,K](bf16) @ BT[Nn,K]^T(bf16), fp32 accum, fused epilogues.
// 256 threads = 4 waves. BK=32. BN=256: waves side-by-side; BM=256/BN=64: stacked.
// CAT: A row r = [A1[(r&rowmask),0:256] | A2[r,0:256]], K=512.
template <int BM, int BN, bool CAT, int EPI>
__global__ __launch_bounds__(256) void mfma_k(
    const bf16* __restrict__ A1, const bf16* __restrict__ A2, unsigned rowmask,
    const bf16* __restrict__ BT, const float* __restrict__ bias,
    float* __restrict__ outF,
    bf16* __restrict__ outB, bf16* __restrict__ outB2,
    const float* __restrict__ g1, const float* __restrict__ b1,
    const float* __restrict__ g2, const float* __restrict__ b2,
    const bf16* __restrict__ resid,
    int M, int K)
{
    constexpr bool LN = (EPI == E_LN1 || EPI == E_LN2);
    constexpr int STAGE_B = (BM * 32 + BN * 32) * 2;
    constexpr int SB = LN ? (64 * 260 * 4) : STAGE_B;
    __shared__ __align__(16) char smem[SB];
    short* As = (short*)smem;
    short* Bs = As + BM * 32;
    float* Cs = (float*)smem;   // LN epilogue reuses staging LDS

    const int tid = threadIdx.x;
    const int wid = tid >> 6, lane = tid & 63;
    const int wr = (BN == 256) ? 0 : wid;
    const int wc = (BN == 256) ? wid : 0;
    const int m0 = blockIdx.x * BM, n0 = blockIdx.y * BN;
    const int srow = tid >> 2;
    const int skoff = (tid & 3) * 8;

    f32x4 acc[4][4] = {};

    for (int k0 = 0; k0 < K; k0 += 32) {
#pragma unroll
        for (int c = 0; c < BM / 64; c++) {
            int r = c * 64 + srow;
            int gr = m0 + r;
            const bf16* p;
            if (CAT) {
                int gk = k0 + skoff;
                p = (gk < 256) ? (A1 + (size_t)(gr & rowmask) * 256 + gk)
                               : (A2 + (size_t)gr * 256 + (gk - 256));
            } else {
                p = A1 + (size_t)gr * K + k0 + skoff;
            }
            *(s16x8*)&As[r * 32 + skoff] = *(const s16x8*)p;
        }
#pragma unroll
        for (int c = 0; c < BN / 64; c++) {
            int r = c * 64 + srow;
            *(s16x8*)&Bs[r * 32 + skoff] =
                *(const s16x8*)(BT + (size_t)(n0 + r) * K + k0 + skoff);
        }
        __syncthreads();
        s16x8 af[4], bf[4];
#pragma unroll
        for (int mi = 0; mi < 4; mi++)
            af[mi] = *(s16x8*)&As[(wr * 64 + mi * 16 + (lane & 15)) * 32 + (lane >> 4) * 8];
#pragma unroll
        for (int ni = 0; ni < 4; ni++)
            bf[ni] = *(s16x8*)&Bs[(wc * 64 + ni * 16 + (lane & 15)) * 32 + (lane >> 4) * 8];
#pragma unroll
        for (int mi = 0; mi < 4; mi++)
#pragma unroll
            for (int ni = 0; ni < 4; ni++)
                acc[mi][ni] = __builtin_amdgcn_mfma_f32_16x16x32_bf16(
                    af[mi], bf[ni], acc[mi][ni], 0, 0, 0);
        __syncthreads();
    }

    if (EPI == E_SILU) {
#pragma unroll
        for (int mi = 0; mi < 4; mi++)
#pragma unroll
            for (int ni = 0; ni < 4; ni++)
#pragma unroll
                for (int r = 0; r < 4; r++) {
                    int row = m0 + wr * 64 + mi * 16 + (lane >> 4) * 4 + r;
                    int col = n0 + wc * 64 + ni * 16 + (lane & 15);
                    float v = acc[mi][ni][r] + bias[col];
                    float s = v / (1.f + __expf(-v));
                    if (col < EE) outB[(size_t)row * EE + col] = f2b(s);
                    else          outB2[(size_t)row * EE + (col - EE)] = f2b(s);
                }
    } else if (EPI == E_BF16) {
#pragma unroll
        for (int mi = 0; mi < 4; mi++)
#pragma unroll
            for (int ni = 0; ni < 4; ni++)
#pragma unroll
                for (int r = 0; r < 4; r++) {
                    int row = m0 + wr * 64 + mi * 16 + (lane >> 4) * 4 + r;
                    int col = n0 + wc * 64 + ni * 16 + (lane & 15);
                    outB[(size_t)row * 256 + col] = f2b(acc[mi][ni][r] + bias[col]);
                }
    } else if (EPI == E_BF16T) {
        // rows r = t*1024+j -> store transposed [t][col][j]
#pragma unroll
        for (int mi = 0; mi < 4; mi++)
#pragma unroll
            for (int ni = 0; ni < 4; ni++)
#pragma unroll
                for (int r = 0; r < 4; r++) {
                    int row = m0 + wr * 64 + mi * 16 + (lane >> 4) * 4 + r;
                    int col = n0 + wc * 64 + ni * 16 + (lane & 15);
                    size_t dst = (((size_t)(row >> 10)) * 256 + col) * 1024 + (row & 1023);
                    outB[dst] = f2b(acc[mi][ni][r] + bias[col]);
                }
    } else if (EPI == E_OUT) {
#pragma unroll
        for (int mi = 0; mi < 4; mi++)
#pragma unroll
            for (int ni = 0; ni < 4; ni++)
#pragma unroll
                for (int r = 0; r < 4; r++) {
                    int row = m0 + wr * 64 + mi * 16 + (lane >> 4) * 4 + r;
                    int col = n0 + wc * 64 + ni * 16 + (lane & 15);
                    float v = acc[mi][ni][r] + bias[col] + toF(resid[(size_t)row * 256 + col]);
                    int t = row & 63, n = row >> 6;
                    outF[((size_t)t * NN_ + n) * 256 + col] = v;
                }
    } else if (EPI == E_TRI) {
        // dbc[M,48]: cols 0-15 d1, 16-31 Bm, 32-47 Cm
#pragma unroll
        for (int mi = 0; mi < 4; mi++)
#pragma unroll
            for (int ni = 0; ni < 4; ni++)
#pragma unroll
                for (int r = 0; r < 4; r++) {
                    int row = m0 + wid * 64 + mi * 16 + (lane >> 4) * 4 + r;
                    int col = ni * 16 + (lane & 15);
                    if (col < 48) {
                        float v = acc[mi][ni][r] + bias[col];
                        outF[(size_t)row * 48 + col] = v;
                    }
                }
    } else {
        // E_LN1 / E_LN2: relu -> Cs, then row LN(s). BM=64, BN=256, grid.y=1.
#pragma unroll
        for (int mi = 0; mi < 4; mi++)
#pragma unroll
            for (int ni = 0; ni < 4; ni++)
#pragma unroll
                for (int r = 0; r < 4; r++) {
                    int rl = mi * 16 + (lane >> 4) * 4 + r;
                    int cl = wc * 64 + ni * 16 + (lane & 15);
                    Cs[rl * 260 + cl] = fmaxf(acc[mi][ni][r] + bias[cl], 0.f);
                }
        __syncthreads();
        float g1v[4], b1v[4], g2v[4], b2v[4];
#pragma unroll
        for (int i = 0; i < 4; i++) {
            g1v[i] = g1[lane * 4 + i];
            b1v[i] = b1[lane * 4 + i];
            if (EPI == E_LN2) { g2v[i] = g2[lane * 4 + i]; b2v[i] = b2[lane * 4 + i]; }
        }
        for (int rr = 0; rr < 16; rr++) {
            int rl = wid * 16 + rr;
            int grow = m0 + rl;
            float x[4];
#pragma unroll
            for (int i = 0; i < 4; i++) x[i] = Cs[rl * 260 + lane * 4 + i];
            float s = x[0] + x[1] + x[2] + x[3];
#pragma unroll
            for (int o = 1; o < 64; o <<= 1) s += __shfl_xor(s, o, 64);
            float mu = s * (1.f / 256.f);
            float d[4], ss = 0.f;
#pragma unroll
            for (int i = 0; i < 4; i++) { d[i] = x[i] - mu; ss = fmaf(d[i], d[i], ss); }
#pragma unroll
            for (int o = 1; o < 64; o <<= 1) ss += __shfl_xor(ss, o, 64);
            float inv = rsqrtf(fmaxf(ss * (1.f / 256.f), 0.f) + 1e-5f);
            float y[4];
#pragma unroll
            for (int i = 0; i < 4; i++) y[i] = d[i] * inv * g1v[i] + b1v[i];
            if (EPI == E_LN1) {
                __align__(8) bf16 pk[4];
#pragma unroll
                for (int i = 0; i < 4; i++) pk[i] = f2b(y[i]);
                *(s16x4*)&outB[(size_t)grow * 256 + lane * 4] = *(s16x4*)pk;
            } else {
                int trow = (grow & 1023) * 64 + (grow >> 10);   // [N,T] order
                __align__(8) bf16 pk[4];
#pragma unroll
                for (int i = 0; i < 4; i++) pk[i] = f2b(y[i]);
                *(s16x4*)&outB[(size_t)trow * 256 + lane * 4] = *(s16x4*)pk;
                float s2 = y[0] + y[1] + y[2] + y[3];
#pragma unroll
                for (int o = 1; o < 64; o <<= 1) s2 += __shfl_xor(s2, o, 64);
                float mu2 = s2 * (1.f / 256.f);
                float d2[4], ss2 = 0.f;
#pragma unroll
                for (int i = 0; i < 4; i++) { d2[i] = y[i] - mu2; ss2 = fmaf(d2[i], d2[i], ss2); }
#pragma unroll
                for (int o = 1; o < 64; o <<= 1) ss2 += __shfl_xor(ss2, o, 64);
                float inv2 = rsqrtf(fmaxf(ss2 * (1.f / 256.f), 0.f) + 1e-5f);
                __align__(8) bf16 pk2[4];
#pragma unroll
                for (int i = 0; i < 4; i++) pk2[i] = f2b(d2[i] * inv2 * g2v[i] + b2v[i]);
                *(s16x4*)&outB2[(size_t)trow * 256 + lane * 4] = *(s16x4*)pk2;
            }
        }
    }
}

// ---------------- dense MFMA aggregation (adj is binary -> exact in bf16) -----------
// Rewritten: BM=128 x BN=256 tile, BK=32, 4 waves (wave tile 64x128).
// grid.x = 512: block -> t = bx>>3, n0 = (bx&7)*128. A[rl,k] built on the fly from
// adj (x gates on the A side: gates depend on (n,k) only -> 8 mults/thread instead
// of 32 on the B side, and B staging becomes a pure s16x8 copy). Register prefetch
// of next K-step's A/B (T14 async-stage split) hides HBM latency under MFMA.
template <bool GATED>
__global__ __launch_bounds__(256, 2) void aggmm_k(
    const float* __restrict__ adj, const float* __restrict__ gates,
    const bf16* __restrict__ BTsrc, bf16* __restrict__ out)
{
    __shared__ __align__(16) short As[128 * 40];
    __shared__ __align__(16) short Bs[256 * 40];
    const int tid = threadIdx.x;
    const int wid = tid >> 6, lane = tid & 63;
    const int wr = wid & 1;          // wave rows: wr*64
    const int wc = wid >> 1;         // wave cols: wc*128
    const int bx = blockIdx.x;
    const int t = bx >> 3, n0 = (bx & 7) * 128;
    const int srow = tid >> 2;       // 0..63
    const int skoff = (tid & 3) * 8; // 0,8,16,24
    const size_t NN2 = (size_t)NN_ * NN_;

    const float* __restrict__ adjB = adj + (size_t)t * NN2 + (size_t)n0 * NN_;
    const float* __restrict__ gB = GATED ? (gates + (size_t)n0 * NN_) : nullptr;
    const bf16* __restrict__ bt = GATED ? BTsrc : (BTsrc + (size_t)t * 256 * 1024);
    const size_t orow0 = (size_t)t * 1024 + n0;

    f32x4 acc[4][8] = {};

    // prefetch registers (next K-step)
    float4 pa[2][2];   // A rows c*64+srow, 8 f32
    float4 pg[2][2];   // gates, same shape (GATED only)
    s16x8 pb[4];       // B rows c*64+srow, 8 bf16

    auto LOADA = [&](int k0) {
#pragma unroll
        for (int c = 0; c < 2; c++) {
            const float* p = adjB + (size_t)(c * 64 + srow) * NN_ + k0 + skoff;
            pa[c][0] = *(const float4*)p;
            pa[c][1] = *(const float4*)(p + 4);
            if (GATED) {
                const float* q = gB + (size_t)(c * 64 + srow) * NN_ + k0 + skoff;
                pg[c][0] = *(const float4*)q;
                pg[c][1] = *(const float4*)(q + 4);
            }
        }
#pragma unroll
        for (int c = 0; c < 4; c++)
            pb[c] = *(const s16x8*)(bt + (size_t)(c * 64 + srow) * 1024 + k0 + skoff);
    };
    auto STORE = [&]() {
#pragma unroll
        for (int c = 0; c < 2; c++) {
            float va[8] = { pa[c][0].x, pa[c][0].y, pa[c][0].z, pa[c][0].w,
                            pa[c][1].x, pa[c][1].y, pa[c][1].z, pa[c][1].w };
            __align__(16) bf16 tmp[8];
            if (GATED) {
                float vg[8] = { pg[c][0].x, pg[c][0].y, pg[c][0].z, pg[c][0].w,
                                pg[c][1].x, pg[c][1].y, pg[c][1].z, pg[c][1].w };
#pragma unroll
                for (int i = 0; i < 8; i++) tmp[i] = f2b(va[i] * vg[i]);
            } else {
#pragma unroll
                for (int i = 0; i < 8; i++) tmp[i] = f2b(va[i]);
            }
            *(s16x8*)&As[(c * 64 + srow) * 40 + skoff] = *(s16x8*)tmp;
        }
#pragma unroll
        for (int c = 0; c < 4; c++)
            *(s16x8*)&Bs[(c * 64 + srow) * 40 + skoff] = pb[c];
    };

    LOADA(0);
#pragma unroll 1
    for (int k0 = 0; k0 < 1024; k0 += 32) {
        STORE();
        __syncthreads();
        if (k0 + 32 < 1024) LOADA(k0 + 32);   // issue next tile; lands before next STORE
        s16x8 af[4];
#pragma unroll
        for (int mi = 0; mi < 4; mi++)
            af[mi] = *(s16x8*)&As[(wr * 64 + mi * 16 + (lane & 15)) * 40 + (lane >> 4) * 8];
#pragma unroll
        for (int ni = 0; ni < 8; ni++) {
            s16x8 bfv = *(s16x8*)&Bs[(wc * 128 + ni * 16 + (lane & 15)) * 40 + (lane >> 4) * 8];
#pragma unroll
            for (int mi = 0; mi < 4; mi++)
                acc[mi][ni] = __builtin_amdgcn_mfma_f32_16x16x32_bf16(
                    af[mi], bfv, acc[mi][ni], 0, 0, 0);
        }
        __syncthreads();
    }

#pragma unroll
    for (int mi = 0; mi < 4; mi++)
#pragma unroll
        for (int ni = 0; ni < 8; ni++)
#pragma unroll
            for (int r = 0; r < 4; r++) {
                int rowl = wr * 64 + mi * 16 + (lane >> 4) * 4 + r;
                int col = wc * 128 + ni * 16 + (lane & 15);
                out[(orow0 + rowl) * 256 + col] = f2b(acc[mi][ni][r]);
            }
}

// ---------------- Mamba selective scan (block = n, thread = e) ----------------------
// dbc[M,48] rows: [d1(16) | Bm(16) | Cm(16)]. n = blockIdx -> dbc addresses are
// wave-uniform -> compiler emits scalar (s_load) reads; u/sg/yg stay coalesced.
__global__ __launch_bounds__(512) void scan_k(
    const bf16* __restrict__ u, const bf16* __restrict__ sg,
    const float* __restrict__ dbc,
    const float* __restrict__ Wdt, const float* __restrict__ bdt,
    const float* __restrict__ Alog, const float* __restrict__ D,
    bf16* __restrict__ yg)
{
    const int n = blockIdx.x, e = threadIdx.x;
    float a[16], wdt[16], h[16];
#pragma unroll
    for (int s = 0; s < 16; s++) {
        a[s] = -__expf(Alog[e * 16 + s]);
        h[s] = 0.f;
    }
#pragma unroll
    for (int k = 0; k < 16; k++) wdt[k] = Wdt[(size_t)k * EE + e];
    const float bdte = bdt[e], De = D[e];
    const float* __restrict__ rowp = dbc + (size_t)n * TT * 48;
    const size_t base = (size_t)n * TT * EE + e;
#pragma unroll 1
    for (int t = 0; t < TT; t++) {
        const float* __restrict__ r = rowp + t * 48;
        float acc = bdte;
#pragma unroll
        for (int k = 0; k < 16; k++) acc = fmaf(r[k], wdt[k], acc);
        float delta = (acc > 20.f) ? acc : __logf(1.f + __expf(acc));
        size_t idx = base + (size_t)t * EE;
        float uv = toF(u[idx]);
        float du = delta * uv;
        float y = 0.f;
#pragma unroll
        for (int s = 0; s < 16; s++) {
            float ad = __expf(delta * a[s]);
            h[s] = fmaf(ad, h[s], du * r[16 + s]);
            y = fmaf(r[32 + s], h[s], y);
        }
        yg[idx] = f2b((y + uv * De) * toF(sg[idx]));
    }
}

// ---------------- prep kernels ------------------------------------------------------
__global__ void cast_k(const float* __restrict__ in, bf16* __restrict__ out, int n) {
    int i = blockIdx.x * 256 + threadIdx.x;
    if (i < n) out[i] = f2b(in[i]);
}
__global__ void transT_k(const float* __restrict__ W, bf16* __restrict__ out, int K, int Nn) {
    int gid = blockIdx.x * 256 + threadIdx.x;
    if (gid >= K * Nn) return;
    int n = gid / K, k = gid - n * K;
    out[gid] = f2b(W[(size_t)k * Nn + n]);
}
__global__ void transmsgs_k(const float* __restrict__ msgs, bf16* __restrict__ msgsT) {
    int gid = blockIdx.x * 256 + threadIdx.x;
    int c = gid >> 10, j = gid & 1023;
    msgsT[gid] = f2b(msgs[(size_t)j * 256 + c]);
}
__global__ void wdbct_k(const float* __restrict__ Wd, const float* __restrict__ WB,
                        const float* __restrict__ WC, bf16* __restrict__ out,
                        const float* __restrict__ bd, const float* __restrict__ bB,
                        const float* __restrict__ bC, float* __restrict__ biascat) {
    int gid = blockIdx.x * 256 + threadIdx.x;
    if (gid < 48) biascat[gid] = (gid < 16) ? bd[gid] : (gid < 32) ? bB[gid - 16] : bC[gid - 32];
    if (gid >= 64 * 512) return;
    int n = gid >> 9, k = gid & 511;
    float v = 0.f;
    if (n < 16)      v = Wd[(size_t)k * 16 + n];
    else if (n < 32) v = WB[(size_t)k * 16 + (n - 16)];
    else if (n < 48) v = WC[(size_t)k * 16 + (n - 32)];
    out[gid] = f2b(v);
}

extern "C" void kernel_launch(void* const* d_in, const int* in_sizes, int n_in,
                              void* d_out, int out_size, void* d_ws, size_t ws_size,
                              hipStream_t stream)
{
    const float* adj   = (const float*)d_in[0];
    const float* pos   = (const float*)d_in[1];
    const float* g1Wm  = (const float*)d_in[2];
    const float* g1bm  = (const float*)d_in[3];
    const float* g1Wq  = (const float*)d_in[4];
    const float* g1Wk  = (const float*)d_in[5];
    const float* g1gb  = (const float*)d_in[6];
    const float* g1Wu  = (const float*)d_in[7];
    const float* g1bu  = (const float*)d_in[8];
    const float* g1lg  = (const float*)d_in[9];
    const float* g1lb  = (const float*)d_in[10];
    const float* g2Wm  = (const float*)d_in[11];
    const float* g2bm  = (const float*)d_in[12];
    const float* g2Wu  = (const float*)d_in[13];
    const float* g2bu  = (const float*)d_in[14];
    const float* g2lg  = (const float*)d_in[15];
    const float* g2lb  = (const float*)d_in[16];
    const float* mlg   = (const float*)d_in[17];
    const float* mlb   = (const float*)d_in[18];
    const float* mWin  = (const float*)d_in[19];
    const float* mbin  = (const float*)d_in[20];
    const float* mWd   = (const float*)d_in[21];
    const float* mbd   = (const float*)d_in[22];
    const float* mWdt  = (const float*)d_in[23];
    const float* mbdt  = (const float*)d_in[24];
    const float* mWB   = (const float*)d_in[25];
    const float* mbB   = (const float*)d_in[26];
    const float* mWC   = (const float*)d_in[27];
    const float* mbC   = (const float*)d_in[28];
    const float* mAlog = (const float*)d_in[29];
    const float* mD    = (const float*)d_in[30];
    const float* mWout = (const float*)d_in[31];
    const float* mbout = (const float*)d_in[32];
    float* out = (float*)d_out;
    char* ws = (char*)d_ws;

    const size_t BIGE = (size_t)TT * NN_ * 256;
    size_t o = 0;
    auto alloc = [&](size_t bytes) { size_t r = o; o += (bytes + 255) & ~(size_t)255; return r; };

    float* msgs  = (float*)(ws + alloc((size_t)NN_ * 256 * 4));
    float* q     = (float*)(ws + alloc((size_t)NN_ * 256 * 4));
    float* kk    = (float*)(ws + alloc((size_t)NN_ * 256 * 4));
    float* gates = (float*)(ws + alloc((size_t)NN_ * NN_ * 4));
    bf16*  Ra    = (bf16*)(ws + alloc(BIGE * 2));                 // agg / xn
    size_t off_x1 = alloc(BIGE * 2);
    bf16*  x1    = (bf16*)(ws + off_x1);
    bf16*  agg2  = (bf16*)(ws + alloc(BIGE * 2));                 // contiguous after x1
    bf16*  x2    = (bf16*)(ws + alloc(BIGE * 2));                 // res, [N,T,H]
    bf16*  yg    = (bf16*)(ws + alloc(BIGE * 2));
    bf16*  sg    = (bf16*)(ws + alloc((size_t)NN_ * TT * EE * 2));
    float* dbc   = (float*)(ws + alloc((size_t)TT * NN_ * 48 * 4));  // [M,48] d1|Bm|Cm
    bf16*  u     = (bf16*)(ws + off_x1);                          // aliases x1+agg2
    // transposed bf16 weights / staging
    bf16* posb   = (bf16*)(ws + alloc((size_t)NN_ * 256 * 2));
    bf16* g1WuT  = (bf16*)(ws + alloc((size_t)256 * 512 * 2));
    bf16* g2WmT  = (bf16*)(ws + alloc((size_t)256 * 256 * 2));
    bf16* g2WuT  = (bf16*)(ws + alloc((size_t)256 * 512 * 2));
    bf16* mWinT  = (bf16*)(ws + alloc((size_t)1024 * 256 * 2));
    bf16* mWoutT = (bf16*)(ws + alloc((size_t)256 * 512 * 2));
    bf16* WdBCT  = (bf16*)(ws + alloc((size_t)64 * 512 * 2));
    float* biascat = (float*)(ws + alloc(64 * 4));
    bf16* msgsT  = (bf16*)(ws + alloc((size_t)256 * 1024 * 2));
    bf16* msgs2T = (bf16*)(ws + alloc(BIGE * 2));

    const unsigned ALLR = 0xFFFFFFFFu;
    const int M = TT * NN_;

    // prep
    cast_k<<<NN_, 256, 0, stream>>>(pos, posb, NN_ * 256);
    transT_k<<<(512 * 256 + 255) / 256, 256, 0, stream>>>(g1Wu, g1WuT, 512, 256);
    transT_k<<<(256 * 256 + 255) / 256, 256, 0, stream>>>(g2Wm, g2WmT, 256, 256);
    transT_k<<<(512 * 256 + 255) / 256, 256, 0, stream>>>(g2Wu, g2WuT, 512, 256);
    transT_k<<<(256 * 1024 + 255) / 256, 256, 0, stream>>>(mWin, mWinT, 256, 1024);
    transT_k<<<(512 * 256 + 255) / 256, 256, 0, stream>>>(mWout, mWoutT, 512, 256);
    wdbct_k<<<(64 * 512 + 255) / 256, 256, 0, stream>>>(mWd, mWB, mWC, WdBCT, mbd, mbB, mbC, biascat);

    // S0: msgs = pos @ g1_Wm + bm (f32)
    gemm_k<false, EPI_F32><<<dim3(16, 4), 256, 0, stream>>>(
        pos, g1Wm, msgs, g1bm, nullptr, 1.f, NN_, 256, 256, 256, 256);
    transmsgs_k<<<1024, 256, 0, stream>>>(msgs, msgsT);
    // S1: q, k
    gemm_k<false, EPI_F32><<<dim3(16, 4), 256, 0, stream>>>(
        msgs, g1Wq, q, nullptr, nullptr, 1.f, NN_, 256, 256, 256, 256);
    gemm_k<false, EPI_F32><<<dim3(16, 4), 256, 0, stream>>>(
        msgs, g1Wk, kk, nullptr, nullptr, 1.f, NN_, 256, 256, 256, 256);
    // S2: gates = sigmoid(q @ k^T / 16 + gb)
    gemm_k<true, EPI_SIG_F32><<<dim3(16, 16), 256, 0, stream>>>(
        q, kk, gates, nullptr, g1gb, 1.f / 16.f, NN_, NN_, 256, 256, 256);
    // S3: agg -> Ra   (BM=128 tile: 8 blocks per t)
    aggmm_k<true><<<512, 256, 0, stream>>>(adj, gates, msgsT, Ra);
    // S4(+S5): x1 = LN(relu(cat(posb,Ra) @ Wu1 + bu1))
    mfma_k<64, 256, true, E_LN1><<<dim3(1024, 1), 256, 0, stream>>>(
        posb, Ra, 1023u, g1WuT, g1bu, nullptr, x1, nullptr,
        g1lg, g1lb, nullptr, nullptr, nullptr, M, 512);
    // S6: msgs2 = x1 @ Wm2 + bm2 -> msgs2T ([t][c][j])
    mfma_k<64, 256, false, E_BF16T><<<dim3(1024, 1), 256, 0, stream>>>(
        x1, x1, ALLR, g2WmT, g2bm, nullptr, msgs2T, nullptr,
        nullptr, nullptr, nullptr, nullptr, nullptr, M, 256);
    // S7: agg2 = adj @ msgs2
    aggmm_k<false><<<512, 256, 0, stream>>>(adj, nullptr, msgs2T, agg2);
    // S8(+S9+S10): x2 = LN(relu(cat(x1,agg2)@Wu2+bu2)) [N,T,H], xn = LN2 -> Ra [N,T,H]
    mfma_k<64, 256, true, E_LN2><<<dim3(1024, 1), 256, 0, stream>>>(
        x1, agg2, ALLR, g2WuT, g2bu, nullptr, x2, Ra,
        g2lg, g2lb, mlg, mlb, nullptr, M, 512);
    // S11: u/sg = silu halves of xn @ Win + bin
    mfma_k<64, 256, false, E_SILU><<<dim3(1024, 4), 256, 0, stream>>>(
        Ra, Ra, ALLR, mWinT, mbin, nullptr, u, sg,
        nullptr, nullptr, nullptr, nullptr, nullptr, M, 256);
    // S12 fused: dbc = u @ [Wd|WB|WC] + biases  ([M,48] interleaved)
    mfma_k<256, 64, false, E_TRI><<<dim3(256, 1), 256, 0, stream>>>(
        u, u, ALLR, WdBCT, biascat, dbc, nullptr, nullptr,
        nullptr, nullptr, nullptr, nullptr, nullptr, M, 512);
    // S13: selective scan -> yg  (block per n, thread per e)
    scan_k<<<NN_, 512, 0, stream>>>(u, sg, dbc, mWdt, mbdt, mAlog, mD, yg);
    // S14: out = yg @ Wout + bout + res -> [T,N,H] f32
    mfma_k<64, 256, false, E_OUT><<<dim3(1024, 1), 256, 0, stream>>>(
        yg, yg, ALLR, mWoutT, mbout, out, nullptr, nullptr,
        nullptr, nullptr, nullptr, nullptr, x2, M, 512);

    (void)in_sizes; (void)n_in; (void)out_size; (void)ws_size;
}